// Round 4
// baseline (948.484 us; speedup 1.0000x reference)
//
#include <hip/hip_runtime.h>
#include <hip/hip_bf16.h>
#include <math.h>

typedef __attribute__((ext_vector_type(8))) short short8;
typedef __attribute__((ext_vector_type(4))) float f32x4;

#define BATCH   2
#define SLEN    2048
#define DMODEL  4096
#define NHEADS  32
#define KVHEADS 8
#define HD      128
#define KVDIM   (KVHEADS*HD)   // 1024
#define MROWS   (BATCH*SLEN)   // 4096

// async global->LDS, 16B per lane, dest = wave-uniform base + lane*16
#define GLDS16(gp, lp) __builtin_amdgcn_global_load_lds( \
    (const __attribute__((address_space(1))) void*)(gp), \
    (__attribute__((address_space(3))) void*)(lp), 16, 0, 0)

static __device__ __forceinline__ unsigned short bf16bits(float x) {
    __hip_bfloat16 h = __float2bfloat16(x);
    return *(unsigned short*)&h;
}
static __device__ __forceinline__ float bf2f(unsigned short u) {
    __hip_bfloat16 h = *(__hip_bfloat16*)&u;
    return __bfloat162float(h);
}

// ---------------- fp32 -> bf16 cast ----------------
__global__ __launch_bounds__(256) void cast_k(const float* __restrict__ in,
                                              unsigned short* __restrict__ out, long n) {
    long i = ((long)blockIdx.x * 256 + threadIdx.x) * 4;
    if (i >= n) return;
    float4 v = *(const float4*)(in + i);
    union { unsigned short h[4]; uint2 u; } c;
    c.h[0] = bf16bits(v.x); c.h[1] = bf16bits(v.y);
    c.h[2] = bf16bits(v.z); c.h[3] = bf16bits(v.w);
    *(uint2*)(out + i) = c.u;
}

// ---------------- RoPE tables ----------------
__global__ void rope_table_k(const int* __restrict__ pos,
                             float* __restrict__ cosT, float* __restrict__ sinT) {
    int s = blockIdx.x;
    int d = threadIdx.x;
    float p = (float)pos[s];
    float inv = powf(10000.0f, -(float)(2 * d) / 128.0f);
    float ang = p * inv;
    cosT[s * 64 + d] = cosf(ang);
    sinT[s * 64 + d] = sinf(ang);
}

// ---------------- RoPE apply in-place on bf16 [M, nh*128] ----------------
__global__ void rope_bf_k(unsigned short* __restrict__ x,
                          const float* __restrict__ cosT, const float* __restrict__ sinT,
                          int nh) {
    int idx = blockIdx.x * 256 + threadIdx.x;
    int d = idx & 63;
    int rest = idx >> 6;
    int h = rest % nh;
    int row = rest / nh;
    int s = row & (SLEN - 1);
    float c  = cosT[s * 64 + d];
    float sn = sinT[s * 64 + d];
    unsigned short* base = x + (size_t)row * (nh * HD) + h * HD;
    float x1 = bf2f(base[d]), x2 = bf2f(base[d + 64]);
    base[d]      = bf16bits(x1 * c - x2 * sn);
    base[d + 64] = bf16bits(x2 * c + x1 * sn);
}

// ---------------- V transpose: bf16 [M][KVDIM] -> bf16 Vt[b*KVH+kvh][d=128][s=2048] ----------------
__global__ __launch_bounds__(256) void vtrans_k(const unsigned short* __restrict__ V,
                                                unsigned short* __restrict__ Vt) {
    __shared__ unsigned short L[64][144];
    const int t = threadIdx.x;
    const int s0 = blockIdx.x * 64;
    const int bk = blockIdx.y;              // b*KVH + kvh
    const int b = bk >> 3, kvh = bk & 7;
    #pragma unroll
    for (int j = 0; j < 4; ++j) {
        int idx = t + j * 256;
        int row = idx >> 4;
        int c8  = (idx & 15) * 8;
        *(short8*)&L[row][c8] =
            *(const short8*)(V + ((size_t)b * SLEN + s0 + row) * KVDIM + kvh * HD + c8);
    }
    __syncthreads();
    {
        int d  = t >> 1;
        int sh = (t & 1) * 32;
        unsigned short tmp[32];
        #pragma unroll
        for (int j = 0; j < 32; ++j) tmp[j] = L[sh + j][d];
        unsigned short* dst = Vt + ((size_t)bk * HD + d) * SLEN + s0 + sh;
        #pragma unroll
        for (int j = 0; j < 4; ++j)
            *(short8*)(dst + j * 8) = *(const short8*)(tmp + j * 8);
    }
}

// ---------------- bf16 MFMA GEMM-NT (m97 structure); CT = float or ushort(bf16) out ----------------
template<typename CT>
__global__ __launch_bounds__(256) void gemm_bf16_nt(
    const unsigned short* __restrict__ A,
    const unsigned short* __restrict__ W,
    CT* __restrict__ C,
    int M, int N, int K)
{
    __shared__ unsigned short As[128 * 32];
    __shared__ unsigned short Bs[128 * 32];
    const int t    = threadIdx.x;
    const int wid  = t >> 6;
    const int lane = t & 63;
    const int m0 = blockIdx.y * 128, n0 = blockIdx.x * 128;
    const int wm = (wid >> 1) * 64, wn = (wid & 1) * 64;

    f32x4 acc[4][4];
    #pragma unroll
    for (int i = 0; i < 4; ++i)
        #pragma unroll
        for (int j = 0; j < 4; ++j)
            acc[i][j] = (f32x4){0.f, 0.f, 0.f, 0.f};

    const int srow  = wid * 16 + (lane >> 2);
    const int skcol = (lane & 3) * 8;
    const unsigned short* Abase = A + (size_t)(m0 + srow) * K + skcol;
    const unsigned short* Wbase = W + (size_t)(n0 + srow) * K + skcol;
    unsigned short* AsB = As + wid * 512;
    unsigned short* BsB = Bs + wid * 512;

    const int frow = lane & 15;
    const int fk   = (lane >> 4) * 8;

    for (int k0 = 0; k0 < K; k0 += 32) {
        __syncthreads();
        GLDS16(Abase + k0,                   AsB);
        GLDS16(Abase + (size_t)64 * K + k0,  AsB + 2048);
        GLDS16(Wbase + k0,                   BsB);
        GLDS16(Wbase + (size_t)64 * K + k0,  BsB + 2048);
        __syncthreads();

        short8 af[4], bfv[4];
        #pragma unroll
        for (int i = 0; i < 4; ++i)
            af[i] = *(const short8*)&As[(wm + i * 16 + frow) * 32 + fk];
        #pragma unroll
        for (int j = 0; j < 4; ++j)
            bfv[j] = *(const short8*)&Bs[(wn + j * 16 + frow) * 32 + fk];
        #pragma unroll
        for (int i = 0; i < 4; ++i)
            #pragma unroll
            for (int j = 0; j < 4; ++j)
                acc[i][j] = __builtin_amdgcn_mfma_f32_16x16x32_bf16(af[i], bfv[j], acc[i][j], 0, 0, 0);
    }

    const int crow = (lane >> 4) * 4, ccol = lane & 15;
    #pragma unroll
    for (int i = 0; i < 4; ++i)
        #pragma unroll
        for (int j = 0; j < 4; ++j) {
            CT* cp = C + (size_t)(m0 + wm + i * 16 + crow) * N + (n0 + wn + j * 16 + ccol);
            #pragma unroll
            for (int r = 0; r < 4; ++r) {
                if constexpr (sizeof(CT) == 2)
                    cp[(size_t)r * N] = bf16bits(acc[i][j][r]);
                else
                    cp[(size_t)r * N] = acc[i][j][r];
            }
        }
}

// ---------------- MFMA flash attention, causal, GQA ----------------
// grid (32, 64); 4 waves; wave w owns Q rows q0+w*16..+15; KVBLK=64.
// Q in registers (direct global load). K LDS rows 256B swizzle (row&15)<<4;
// Vt/P LDS rows 128B swizzle (row&7)<<4. LDS 40KB -> 4 blocks/CU.
__global__ __launch_bounds__(256) void flash_mfma(
    const unsigned short* __restrict__ Qb,   // [MROWS][DMODEL] bf16 (rope'd)
    const unsigned short* __restrict__ Kb,   // [MROWS][KVDIM] bf16 (rope'd)
    const unsigned short* __restrict__ Vt,   // [B*KVH][HD][SLEN] bf16
    unsigned short* __restrict__ Ob)         // [MROWS][DMODEL] bf16
{
    __shared__ unsigned short Ks[64 * 128];
    __shared__ unsigned short Vs[128 * 64];
    __shared__ unsigned short Ps[4][16 * 64];

    const int t = threadIdx.x;
    const int wid = t >> 6, lane = t & 63;
    const int qt = gridDim.x - 1 - blockIdx.x;    // heavy blocks first
    const int bh = blockIdx.y;
    const int b = bh >> 5, h = bh & 31, kvh = h >> 2;
    const int q0 = qt * 64;
    const size_t qrow = (size_t)b * SLEN + q0;
    const int fr = lane & 15;
    const int hi16 = (lane >> 4) << 4;            // byte slice base 0,16,32,48

    // ---- Q fragments straight to registers (once per block)
    short8 qf[4];
    {
        const unsigned short* qp = Qb + (qrow + wid * 16 + fr) * DMODEL + h * HD + (lane >> 4) * 8;
        #pragma unroll
        for (int ks = 0; ks < 4; ++ks)
            qf[ks] = *(const short8*)(qp + ks * 32);
    }

    f32x4 accO[8];
    #pragma unroll
    for (int db = 0; db < 8; ++db) accO[db] = (f32x4){0.f, 0.f, 0.f, 0.f};
    float m_i[4] = {-INFINITY, -INFINITY, -INFINITY, -INFINITY};
    float l_i[4] = {0.f, 0.f, 0.f, 0.f};
    const float scale = 0.088388347648318447f;

    const unsigned short* Kg0 = Kb + (size_t)b * SLEN * KVDIM + kvh * HD;
    const unsigned short* Vg0 = Vt + (size_t)(b * KVHEADS + kvh) * HD * SLEN;

    for (int kt = 0; kt <= qt; ++kt) {
        __syncthreads();   // all waves done reading Ks/Vs of previous tile
        {
            const unsigned short* Kg = Kg0 + (size_t)kt * 64 * KVDIM;
            #pragma unroll
            for (int i = 0; i < 4; ++i) {
                int row = i * 16 + (t >> 4);
                int colel = ((((t & 15) << 4) ^ ((row & 15) << 4)) >> 1);
                GLDS16(Kg + (size_t)row * KVDIM + colel, Ks + i * 2048 + wid * 512);
            }
            const unsigned short* Vg = Vg0 + kt * 64;
            #pragma unroll
            for (int i = 0; i < 4; ++i) {
                int row = i * 32 + (t >> 3);
                int colel = ((((t & 7) << 4) ^ ((row & 7) << 4)) >> 1);
                GLDS16(Vg + (size_t)row * SLEN + colel, Vs + i * 2048 + wid * 512);
            }
        }
        __syncthreads();

        // ---- QK^T: 16 MFMA
        f32x4 sc[4];
        __builtin_amdgcn_s_setprio(1);
        #pragma unroll
        for (int cb = 0; cb < 4; ++cb) {
            sc[cb] = (f32x4){0.f, 0.f, 0.f, 0.f};
            int krow = cb * 16 + fr;
            const unsigned short* kp = Ks + krow * 128;
            int sw = (krow & 15) << 4;
            #pragma unroll
            for (int ks = 0; ks < 4; ++ks) {
                int pb = (ks * 64 + hi16) ^ sw;
                short8 kf = *(const short8*)(kp + (pb >> 1));
                sc[cb] = __builtin_amdgcn_mfma_f32_16x16x32_bf16(qf[ks], kf, sc[cb], 0, 0, 0);
            }
        }
        __builtin_amdgcn_s_setprio(0);

        // ---- mask + scale
        if (kt == qt) {
            #pragma unroll
            for (int cb = 0; cb < 4; ++cb)
                #pragma unroll
                for (int r = 0; r < 4; ++r) {
                    int kg = cb * 16 + fr;
                    int qg = wid * 16 + (lane >> 4) * 4 + r;
                    sc[cb][r] = (kg <= qg) ? sc[cb][r] * scale : -INFINITY;
                }
        } else {
            #pragma unroll
            for (int cb = 0; cb < 4; ++cb)
                #pragma unroll
                for (int r = 0; r < 4; ++r) sc[cb][r] *= scale;
        }

        // ---- online softmax with defer-max (T13, THR=8)
        float pmax[4];
        #pragma unroll
        for (int r = 0; r < 4; ++r)
            pmax[r] = fmaxf(fmaxf(sc[0][r], sc[1][r]), fmaxf(sc[2][r], sc[3][r]));
        #pragma unroll
        for (int m = 1; m < 16; m <<= 1)
            #pragma unroll
            for (int r = 0; r < 4; ++r)
                pmax[r] = fmaxf(pmax[r], __shfl_xor(pmax[r], m));

        bool ok = true;
        #pragma unroll
        for (int r = 0; r < 4; ++r) ok = ok && (pmax[r] <= m_i[r] + 8.0f);
        if (!__all(ok)) {
            #pragma unroll
            for (int r = 0; r < 4; ++r) {
                float mn = fmaxf(m_i[r], pmax[r]);
                float al = __expf(m_i[r] - mn);
                m_i[r] = mn;
                l_i[r] *= al;
                #pragma unroll
                for (int db = 0; db < 8; ++db) accO[db][r] *= al;
            }
        }

        float rsum[4] = {0.f, 0.f, 0.f, 0.f};
        #pragma unroll
        for (int cb = 0; cb < 4; ++cb)
            #pragma unroll
            for (int r = 0; r < 4; ++r) {
                float p = __expf(sc[cb][r] - m_i[r]);
                sc[cb][r] = p;
                rsum[r] += p;
            }
        #pragma unroll
        for (int m = 1; m < 16; m <<= 1)
            #pragma unroll
            for (int r = 0; r < 4; ++r)
                rsum[r] += __shfl_xor(rsum[r], m);
        #pragma unroll
        for (int r = 0; r < 4; ++r)
            l_i[r] += rsum[r];

        // ---- P -> per-wave LDS (bf16, swizzled)
        {
            unsigned short* pw = Ps[wid];
            #pragma unroll
            for (int r = 0; r < 4; ++r) {
                int qr = (lane >> 4) * 4 + r;
                int sw = (qr & 7) << 4;
                #pragma unroll
                for (int cb = 0; cb < 4; ++cb) {
                    int pb = (cb * 32 + ((lane & 15) << 1)) ^ sw;
                    pw[qr * 64 + (pb >> 1)] = bf16bits(sc[cb][r]);
                }
            }
        }

        // ---- PV: 16 MFMA
        {
            const unsigned short* pr = Ps[wid];
            short8 pa[2];
            int swp = (fr & 7) << 4;
            #pragma unroll
            for (int ks = 0; ks < 2; ++ks) {
                int pb = (ks * 64 + hi16) ^ swp;
                pa[ks] = *(const short8*)(pr + fr * 64 + (pb >> 1));
            }
            __builtin_amdgcn_s_setprio(1);
            #pragma unroll
            for (int db = 0; db < 8; ++db) {
                int vrow = db * 16 + fr;
                const unsigned short* vp = Vs + vrow * 64;
                int sw = (vrow & 7) << 4;
                #pragma unroll
                for (int ks = 0; ks < 2; ++ks) {
                    int pb = (ks * 64 + hi16) ^ sw;
                    short8 vf = *(const short8*)(vp + (pb >> 1));
                    accO[db] = __builtin_amdgcn_mfma_f32_16x16x32_bf16(pa[ks], vf, accO[db], 0, 0, 0);
                }
            }
            __builtin_amdgcn_s_setprio(0);
        }
    }

    // ---- epilogue
    float inv[4];
    #pragma unroll
    for (int r = 0; r < 4; ++r) inv[r] = 1.0f / l_i[r];
    unsigned short* Og = Ob + (qrow + wid * 16 + (lane >> 4) * 4) * DMODEL + h * HD + fr;
    #pragma unroll
    for (int r = 0; r < 4; ++r)
        #pragma unroll
        for (int db = 0; db < 8; ++db)
            Og[(size_t)r * DMODEL + db * 16] = bf16bits(accO[db][r] * inv[r]);
}

extern "C" void kernel_launch(void* const* d_in, const int* in_sizes, int n_in,
                              void* d_out, int out_size, void* d_ws, size_t ws_size,
                              hipStream_t stream) {
    const float* hs  = (const float*)d_in[0];
    const int*   pos = (const int*)d_in[1];
    const float* wq  = (const float*)d_in[2];
    const float* wk  = (const float*)d_in[3];
    const float* wv  = (const float*)d_in[4];
    const float* wo  = (const float*)d_in[5];
    float* out = (float*)d_out;

    char* ws = (char*)d_ws;
    unsigned short* hs_bf  = (unsigned short*)(ws);                       // 32 MB
    unsigned short* wqo_bf = (unsigned short*)(ws + ((size_t)32  << 20)); // 32 MB (wq then wo)
    unsigned short* wk_bf  = (unsigned short*)(ws + ((size_t)64  << 20)); // 8 MB
    unsigned short* wv_bf  = (unsigned short*)(ws + ((size_t)72  << 20)); // 8 MB
    unsigned short* Qbf    = (unsigned short*)(ws + ((size_t)80  << 20)); // 32 MB (bf16, rope in-place)
    unsigned short* Kbf    = (unsigned short*)(ws + ((size_t)112 << 20)); // 8 MB
    unsigned short* Vbf    = (unsigned short*)(ws + ((size_t)120 << 20)); // 8 MB
    unsigned short* Vtb    = (unsigned short*)(ws + ((size_t)128 << 20)); // 8 MB
    unsigned short* Obf    = (unsigned short*)(ws + ((size_t)136 << 20)); // 32 MB
    float*          cosT   = (float*)(ws + ((size_t)168 << 20));          // 512 KB
    float*          sinT   = (float*)(ws + ((size_t)168 << 20) + (size_t)SLEN * 64 * 4);
    // total ~169 MB

    const long nHS = (long)MROWS * DMODEL;
    const long nWQ = (long)DMODEL * DMODEL;
    const long nWK = (long)KVDIM * DMODEL;

    rope_table_k<<<SLEN, 64, 0, stream>>>(pos, cosT, sinT);

    cast_k<<<nHS / 4 / 256, 256, 0, stream>>>(hs, hs_bf, nHS);
    cast_k<<<nWQ / 4 / 256, 256, 0, stream>>>(wq, wqo_bf, nWQ);
    cast_k<<<nWK / 4 / 256, 256, 0, stream>>>(wk, wk_bf, nWK);
    cast_k<<<nWK / 4 / 256, 256, 0, stream>>>(wv, wv_bf, nWK);

    dim3 blk(256);
    gemm_bf16_nt<unsigned short><<<dim3(DMODEL/128, MROWS/128), blk, 0, stream>>>(hs_bf, wqo_bf, Qbf, MROWS, DMODEL, DMODEL);
    cast_k<<<nWQ / 4 / 256, 256, 0, stream>>>(wo, wqo_bf, nWQ);
    gemm_bf16_nt<unsigned short><<<dim3(KVDIM/128,  MROWS/128), blk, 0, stream>>>(hs_bf, wk_bf, Kbf, MROWS, KVDIM, DMODEL);
    gemm_bf16_nt<unsigned short><<<dim3(KVDIM/128,  MROWS/128), blk, 0, stream>>>(hs_bf, wv_bf, Vbf, MROWS, KVDIM, DMODEL);

    rope_bf_k<<<(MROWS * NHEADS  * 64) / 256, 256, 0, stream>>>(Qbf, cosT, sinT, NHEADS);
    rope_bf_k<<<(MROWS * KVHEADS * 64) / 256, 256, 0, stream>>>(Kbf, cosT, sinT, KVHEADS);
    vtrans_k<<<dim3(SLEN/64, BATCH*KVHEADS), blk, 0, stream>>>(Vbf, Vtb);

    flash_mfma<<<dim3(SLEN/64, BATCH*NHEADS), blk, 0, stream>>>(Qbf, Kbf, Vtb, Obf);

    gemm_bf16_nt<float><<<dim3(DMODEL/128, MROWS/128), blk, 0, stream>>>(Obf, wqo_bf, out, MROWS, DMODEL, DMODEL);
}